// Round 16
// baseline (32276.605 us; speedup 1.0000x reference)
//
#include <hip/hip_runtime.h>

// VanillaRNN — bit-exact specialized kernel, R16 (roofline-discriminating probe).
// Reference arithmetic (oracle winner v=75, verified bit-exact full-batch R6):
//   GEMM: per column, TWO k-panels {0..511},{512..1023}; each an independent
//         ascending-k FMA chain from 0; G = s0 + s1 (single commutative add).
//   z    = fma(x_t, w_c, G) + b_c
//   tanh = XLA FastTanh FMA-Horner, clamp ±7.99881172180175781, |x|<4e-4 -> x,
//          IEEE f32 divide.
// DO NOT reorder any FP op in the recurrence.
//
// R15 plateau analysis: VALU busy-time 21.0 ms == 2.2e12 FLOP / 103 TF
// (m07 measured FMA ceiling) -> maybe already FMA-issue-bound (reading A),
// or 14 ms FMA + 7 ms aux (reading B). R16 discriminates:
//  (1) QUAD-rotating W buffers A/B/C/D, 3-group (~768 cyc) lookahead;
//      rotation by naming -> zero v_mov copies; cross-step prefetch keeps
//      the pipeline primed through both barriers.
//  (2) readfirstlane-pinned uniform W base -> SALU-advanced addressing.
// FP chains bit-identical (groups consumed in ascending k order).
// Shape: 256 blocks x 512 threads (2 waves/SIMD), W traffic-optimal.
// Floors: FMA 14 ms (spec) / 21.4 ms (m07 measured), L2 ~15 ms.

#define SEQ   512
#define HID   1024
#define NCLS  10
#define TPB   512
#define ROWS  8
#define CLAMPV 7.99881172180175781f

__device__ __forceinline__ float tanh_win(float x) {
#pragma clang fp contract(off)
    float xc = fminf(fmaxf(x, -CLAMPV), CLAMPV);
    float x2 = xc * xc;
    float p = -2.76076847742355e-16f;
    p = __fmaf_rn(x2, p,  2.00018790482477e-13f);
    p = __fmaf_rn(x2, p, -8.60467152213735e-11f);
    p = __fmaf_rn(x2, p,  5.12229709037114e-08f);
    p = __fmaf_rn(x2, p,  1.48572235717979e-05f);
    p = __fmaf_rn(x2, p,  6.37261928875436e-04f);
    p = __fmaf_rn(x2, p,  4.89352455891786e-03f);
    p = xc * p;
    float q = 1.19825839466702e-06f;
    q = __fmaf_rn(x2, q,  1.18534705686654e-04f);
    q = __fmaf_rn(x2, q,  2.26843463243900e-03f);
    q = __fmaf_rn(x2, q,  4.89352518554385e-03f);
    float r = p / q;                      // IEEE f32 divide
    return (fabsf(x) < 0.0004f) ? x : r;  // passthrough on unclamped x
}

#define MAC4(hv, wv)                              \
    sv.x = __fmaf_rn((hv), (wv).x, sv.x);         \
    sv.y = __fmaf_rn((hv), (wv).y, sv.y);         \
    sv.z = __fmaf_rn((hv), (wv).z, sv.z);         \
    sv.w = __fmaf_rn((hv), (wv).w, sv.w);

// Load one 4-k-row W group at compile-time row offset R0 from uniform ptr P.
#define LOADG(N, P, R0)                                                        \
    N##0 = *reinterpret_cast<const float4*>((P) + ((R0)    ) * HID + c0);      \
    N##1 = *reinterpret_cast<const float4*>((P) + ((R0) + 1) * HID + c0);      \
    N##2 = *reinterpret_cast<const float4*>((P) + ((R0) + 2) * HID + c0);     \
    N##3 = *reinterpret_cast<const float4*>((P) + ((R0) + 3) * HID + c0);

// FMA one 4-k group (buffer N) into all 8 rows' chains; h read at iter-local
// compile-time offset J from hj. Ascending k per (row,col) chain — FP
// sequence identical to R9/R10/R15 (bit-exact).
#define FMAG(N, J)                                                             \
    {                                                                          \
        _Pragma("unroll")                                                      \
        for (int r = 0; r < ROWS; ++r) {                                       \
            const float4 ha =                                                  \
                *reinterpret_cast<const float4*>(hj + r * HID + (J));          \
            float4 sv = s[r];                                                  \
            MAC4(ha.x, N##0); MAC4(ha.y, N##1);                                \
            MAC4(ha.z, N##2); MAC4(ha.w, N##3);                                \
            s[r] = sv;                                                         \
        }                                                                      \
    }

// Finish one row: g = s_own + s_other; z = fma(x,w,g)+b; h = tanh(z).
#define FINISH_ROW(ROW)                                                        \
    {                                                                          \
        const float4 so = *reinterpret_cast<const float4*>(&sb[(ROW) * HID + c0]); \
        const float xv = xl[(ROW) * SEQ + t];                                  \
        float4 g;                                                              \
        g.x = s[ROW].x + so.x;                                                 \
        g.y = s[ROW].y + so.y;                                                 \
        g.z = s[ROW].z + so.z;                                                 \
        g.w = s[ROW].w + so.w;                                                 \
        float4 hn;                                                             \
        hn.x = tanh_win(__fmaf_rn(xv, w4.x, g.x) + b4.x);                      \
        hn.y = tanh_win(__fmaf_rn(xv, w4.y, g.y) + b4.y);                      \
        hn.z = tanh_win(__fmaf_rn(xv, w4.z, g.z) + b4.z);                      \
        hn.w = tanh_win(__fmaf_rn(xv, w4.w, g.w) + b4.w);                      \
        *reinterpret_cast<float4*>(&hl[(ROW) * HID + c0]) = hn;                \
    }

__launch_bounds__(TPB, 1)
__global__ void rnn_win(const float* __restrict__ x, const float* __restrict__ W_hx,
                        const float* __restrict__ Whh, const float* __restrict__ W_ph,
                        const float* __restrict__ bh, const float* __restrict__ bp,
                        float* __restrict__ out) {
#pragma clang fp contract(off)
    __shared__ float hl[ROWS * HID];   // 32 KB  current hidden state
    __shared__ float xl[ROWS * SEQ];   // 16 KB  staged inputs
    __shared__ float sb[ROWS * HID];   // 32 KB  cross-panel subtotal exchange
    const int tid  = threadIdx.x;
    const int blk  = blockIdx.x;
    const int col  = tid & 255;        // colgroup id
    const int pp   = tid >> 8;         // panel id: 0 -> k 0..511, 1 -> k 512..1023
    const int c0   = col * 4;
    const int row0 = blk * ROWS;

    for (int i = tid; i < ROWS * SEQ; i += TPB) xl[i] = x[(size_t)row0 * SEQ + i];
    for (int i = tid; i < ROWS * HID; i += TPB) hl[i] = 0.0f;

    const float4 w4 = *reinterpret_cast<const float4*>(W_hx + c0);
    const float4 b4 = *reinterpret_cast<const float4*>(bh + c0);
    // wave-uniform panel base, pinned to SGPR via readfirstlane
    const unsigned pbase = (unsigned)__builtin_amdgcn_readfirstlane(pp * (512 * HID));
    const float* __restrict__ wp0 = Whh + pbase;
    __syncthreads();

    float4 A0, A1, A2, A3, B0, B1, B2, B3, C0, C1, C2, C3, D0, D1, D2, D3;
    LOADG(A, wp0, 0);                  // groups 0..2 of step 0
    LOADG(B, wp0, 4);
    LOADG(C, wp0, 8);

    for (int t = 0; t < SEQ; ++t) {
        float4 s[ROWS];
        #pragma unroll
        for (int r = 0; r < ROWS; ++r) s[r] = float4{0.f, 0.f, 0.f, 0.f};

        const float* wp = wp0;             // uniform, SALU-advanced
        const float* hj = &hl[pp * 512];   // LDS base, one v_add per iter
        // 31 iters x 4 groups (g0..g123); lookahead = 3 groups (~768 FMA-cyc).
        #pragma unroll 1
        for (int i = 0; i < 31; ++i) {
            LOADG(D, wp, 12);  FMAG(A, 0);     // load g4i+3, fma g4i
            LOADG(A, wp, 16);  FMAG(B, 4);     // load g4i+4, fma g4i+1
            LOADG(B, wp, 20);  FMAG(C, 8);     // load g4i+5, fma g4i+2
            LOADG(C, wp, 24);  FMAG(D, 12);    // load g4i+6, fma g4i+3
            wp += 16 * HID;
            hj += 16;
        }
        // tail: A=g124, B=g125, C=g126; D <- g127; prefetch next step's g0..g2
        LOADG(D, wp, 12);
        FMAG(A, 0);                            // g124 (j=496..499)
        LOADG(A, wp0, 0);                      // next-step group 0
        FMAG(B, 4);                            // g125
        LOADG(B, wp0, 4);                      // next-step group 1
        FMAG(C, 8);                            // g126
        LOADG(C, wp0, 8);                      // next-step group 2
        FMAG(D, 12);                           // g127

        // publish the half the OTHER panel-group finishes (static indices)
        if (pp == 0) {
            *reinterpret_cast<float4*>(&sb[4 * HID + c0]) = s[4];
            *reinterpret_cast<float4*>(&sb[5 * HID + c0]) = s[5];
            *reinterpret_cast<float4*>(&sb[6 * HID + c0]) = s[6];
            *reinterpret_cast<float4*>(&sb[7 * HID + c0]) = s[7];
        } else {
            *reinterpret_cast<float4*>(&sb[0 * HID + c0]) = s[0];
            *reinterpret_cast<float4*>(&sb[1 * HID + c0]) = s[1];
            *reinterpret_cast<float4*>(&sb[2 * HID + c0]) = s[2];
            *reinterpret_cast<float4*>(&sb[3 * HID + c0]) = s[3];
        }
        __syncthreads();   // h_t reads done; sb halves visible

        // finish own half (static indices; g = s_own + s_other, commutative)
        if (pp == 0) {
            FINISH_ROW(0); FINISH_ROW(1); FINISH_ROW(2); FINISH_ROW(3);
        } else {
            FINISH_ROW(4); FINISH_ROW(5); FINISH_ROW(6); FINISH_ROW(7);
        }
        __syncthreads();   // h_{t+1} visible to all
    }

    // Epilogue: out = h_T @ W_ph + b_p (order-insensitive at bf16 threshold)
    if (tid < ROWS * NCLS) {
        const int r = tid / NCLS, k = tid - r * NCLS;
        float acc = bp[k];
        for (int j = 0; j < HID; ++j)
            acc = __fmaf_rn(hl[r * HID + j], W_ph[j * NCLS + k], acc);
        out[(size_t)(row0 + r) * NCLS + k] = acc;
    }
}

extern "C" void kernel_launch(void* const* d_in, const int* in_sizes, int n_in,
                              void* d_out, int out_size, void* d_ws, size_t ws_size,
                              hipStream_t stream) {
    const float* x    = (const float*)d_in[0];
    const float* W_hx = (const float*)d_in[1];
    const float* Whh  = (const float*)d_in[2];
    const float* W_ph = (const float*)d_in[3];
    const float* bh   = (const float*)d_in[4];
    const float* bp   = (const float*)d_in[5];
    float* out = (float*)d_out;

    rnn_win<<<2048 / ROWS, TPB, 0, stream>>>(x, W_hx, Whh, W_ph, bh, bp, out);
}

// Round 17
// 29804.327 us; speedup vs baseline: 1.0830x; 1.0830x over previous
//
#include <hip/hip_runtime.h>

// VanillaRNN — bit-exact specialized kernel, R17: 8 cols/thread (ds-pipe relief).
// Reference arithmetic (oracle winner v=75, verified bit-exact full-batch R6):
//   GEMM: per column, TWO k-panels {0..511},{512..1023}; each an independent
//         ascending-k FMA chain from 0; G = s0 + s1 (single commutative add).
//   z    = fma(x_t, w_c, G) + b_c
//   tanh = XLA FastTanh FMA-Horner, clamp ±7.99881172180175781, |x|<4e-4 -> x,
//          IEEE f32 divide.
// DO NOT reorder any FP op in the recurrence.
//
// R16 post-mortem: quad-buffer spilled (FETCH 16 GB). New model: at 4 cols/
// thread the LDS return path (8192 ds_read_b128/CU-step ~ 98k cyc at 12 cyc)
// co-saturates with VALU at 76% — both pipes pinned, explaining the R10-R16
// plateau. R17 halves ds instrs AND aux per FMA: 8 cols/thread, TPB=256
// (1 wave/SIMD), R15 schedule (triple-buffer, 2-group lookahead = 1024 FMA-
// cyc, SALU-uniform W base, immediate-offset ds reads, cross-step prefetch).
// W traffic per CU unchanged. Budget: ~72k cyc/SIMD-step -> ~16-19 ms.

#define SEQ   512
#define HID   1024
#define NCLS  10
#define TPB   256
#define ROWS  8
#define CLAMPV 7.99881172180175781f

__device__ __forceinline__ float tanh_win(float x) {
#pragma clang fp contract(off)
    float xc = fminf(fmaxf(x, -CLAMPV), CLAMPV);
    float x2 = xc * xc;
    float p = -2.76076847742355e-16f;
    p = __fmaf_rn(x2, p,  2.00018790482477e-13f);
    p = __fmaf_rn(x2, p, -8.60467152213735e-11f);
    p = __fmaf_rn(x2, p,  5.12229709037114e-08f);
    p = __fmaf_rn(x2, p,  1.48572235717979e-05f);
    p = __fmaf_rn(x2, p,  6.37261928875436e-04f);
    p = __fmaf_rn(x2, p,  4.89352455891786e-03f);
    p = xc * p;
    float q = 1.19825839466702e-06f;
    q = __fmaf_rn(x2, q,  1.18534705686654e-04f);
    q = __fmaf_rn(x2, q,  2.26843463243900e-03f);
    q = __fmaf_rn(x2, q,  4.89352518554385e-03f);
    float r = p / q;                      // IEEE f32 divide
    return (fabsf(x) < 0.0004f) ? x : r;  // passthrough on unclamped x
}

#define MAC4V(hv, wv, sv)                          \
    sv.x = __fmaf_rn((hv), (wv).x, sv.x);          \
    sv.y = __fmaf_rn((hv), (wv).y, sv.y);          \
    sv.z = __fmaf_rn((hv), (wv).z, sv.z);          \
    sv.w = __fmaf_rn((hv), (wv).w, sv.w);

// Load one 4-k-row x 8-col W group at compile-time row offset R0 from P.
#define LOADG(N, P, R0)                                                        \
    N##00 = *reinterpret_cast<const float4*>((P) + ((R0)    ) * HID + c0);     \
    N##01 = *reinterpret_cast<const float4*>((P) + ((R0)    ) * HID + c0 + 4); \
    N##10 = *reinterpret_cast<const float4*>((P) + ((R0) + 1) * HID + c0);     \
    N##11 = *reinterpret_cast<const float4*>((P) + ((R0) + 1) * HID + c0 + 4); \
    N##20 = *reinterpret_cast<const float4*>((P) + ((R0) + 2) * HID + c0);     \
    N##21 = *reinterpret_cast<const float4*>((P) + ((R0) + 2) * HID + c0 + 4); \
    N##30 = *reinterpret_cast<const float4*>((P) + ((R0) + 3) * HID + c0);     \
    N##31 = *reinterpret_cast<const float4*>((P) + ((R0) + 3) * HID + c0 + 4);

// FMA one 4-k group (buffer N) into all 8 rows' chains, 8 cols/thread.
// h read at iter-local compile-time offset J. Ascending k per (row,col)
// chain — FP sequence identical to R9..R15 (bit-exact).
#define FMAG(N, J)                                                             \
    {                                                                          \
        _Pragma("unroll")                                                      \
        for (int r = 0; r < ROWS; ++r) {                                       \
            const float4 ha =                                                  \
                *reinterpret_cast<const float4*>(hj + r * HID + (J));          \
            float4 sa = s0[r], sbv = s1[r];                                    \
            MAC4V(ha.x, N##00, sa); MAC4V(ha.x, N##01, sbv);                   \
            MAC4V(ha.y, N##10, sa); MAC4V(ha.y, N##11, sbv);                   \
            MAC4V(ha.z, N##20, sa); MAC4V(ha.z, N##21, sbv);                   \
            MAC4V(ha.w, N##30, sa); MAC4V(ha.w, N##31, sbv);                   \
            s0[r] = sa; s1[r] = sbv;                                           \
        }                                                                      \
    }

#define ACOPY()                                                                \
    A00 = C00; A01 = C01; A10 = C10; A11 = C11;                                \
    A20 = C20; A21 = C21; A30 = C30; A31 = C31;

#define PUBROW(R)                                                              \
    *reinterpret_cast<float4*>(&sb[(R) * HID + c0])     = s0[R];               \
    *reinterpret_cast<float4*>(&sb[(R) * HID + c0 + 4]) = s1[R];

// Finish one row (8 cols): g = s_own + s_other; z = fma(x,w,g)+b; h = tanh(z).
#define FINISH_ROW(R)                                                          \
    {                                                                          \
        const float4 so0 = *reinterpret_cast<const float4*>(&sb[(R) * HID + c0]);     \
        const float4 so1 = *reinterpret_cast<const float4*>(&sb[(R) * HID + c0 + 4]); \
        const float xv = xl[(R) * SEQ + t];                                    \
        float4 g0, g1;                                                         \
        g0.x = s0[R].x + so0.x; g0.y = s0[R].y + so0.y;                        \
        g0.z = s0[R].z + so0.z; g0.w = s0[R].w + so0.w;                        \
        g1.x = s1[R].x + so1.x; g1.y = s1[R].y + so1.y;                        \
        g1.z = s1[R].z + so1.z; g1.w = s1[R].w + so1.w;                        \
        float4 h0, h1;                                                         \
        h0.x = tanh_win(__fmaf_rn(xv, wqa.x, g0.x) + bqa.x);                   \
        h0.y = tanh_win(__fmaf_rn(xv, wqa.y, g0.y) + bqa.y);                   \
        h0.z = tanh_win(__fmaf_rn(xv, wqa.z, g0.z) + bqa.z);                   \
        h0.w = tanh_win(__fmaf_rn(xv, wqa.w, g0.w) + bqa.w);                   \
        h1.x = tanh_win(__fmaf_rn(xv, wqb.x, g1.x) + bqb.x);                   \
        h1.y = tanh_win(__fmaf_rn(xv, wqb.y, g1.y) + bqb.y);                   \
        h1.z = tanh_win(__fmaf_rn(xv, wqb.z, g1.z) + bqb.z);                   \
        h1.w = tanh_win(__fmaf_rn(xv, wqb.w, g1.w) + bqb.w);                   \
        *reinterpret_cast<float4*>(&hl[(R) * HID + c0])     = h0;              \
        *reinterpret_cast<float4*>(&hl[(R) * HID + c0 + 4]) = h1;              \
    }

__launch_bounds__(TPB, 1)
__global__ void rnn_win(const float* __restrict__ x, const float* __restrict__ W_hx,
                        const float* __restrict__ Whh, const float* __restrict__ W_ph,
                        const float* __restrict__ bh, const float* __restrict__ bp,
                        float* __restrict__ out) {
#pragma clang fp contract(off)
    __shared__ float hl[ROWS * HID];   // 32 KB  current hidden state
    __shared__ float xl[ROWS * SEQ];   // 16 KB  staged inputs
    __shared__ float sb[ROWS * HID];   // 32 KB  cross-panel subtotal exchange
    const int tid  = threadIdx.x;
    const int blk  = blockIdx.x;
    const int col  = tid & 127;        // colgroup id (8 cols each)
    const int pp   = tid >> 7;         // panel id: 0 -> k 0..511, 1 -> k 512..1023
    const int c0   = col * 8;
    const int row0 = blk * ROWS;

    for (int i = tid; i < ROWS * SEQ; i += TPB) xl[i] = x[(size_t)row0 * SEQ + i];
    for (int i = tid; i < ROWS * HID; i += TPB) hl[i] = 0.0f;

    const float4 wqa = *reinterpret_cast<const float4*>(W_hx + c0);
    const float4 wqb = *reinterpret_cast<const float4*>(W_hx + c0 + 4);
    const float4 bqa = *reinterpret_cast<const float4*>(bh + c0);
    const float4 bqb = *reinterpret_cast<const float4*>(bh + c0 + 4);
    // wave-uniform panel base, pinned to SGPR
    const unsigned pbase = (unsigned)__builtin_amdgcn_readfirstlane(pp * (512 * HID));
    const float* __restrict__ wp0 = Whh + pbase;
    __syncthreads();

    float4 A00, A01, A10, A11, A20, A21, A30, A31;
    float4 B00, B01, B10, B11, B20, B21, B30, B31;
    float4 C00, C01, C10, C11, C20, C21, C30, C31;
    LOADG(C, wp0, 0);                  // group 0 of step 0

    for (int t = 0; t < SEQ; ++t) {
        // step prologue: A <- C (group 0, prefetched last step); issue group 1
        ACOPY();
        LOADG(B, wp0, 4);

        float4 s0[ROWS], s1[ROWS];
        #pragma unroll
        for (int r = 0; r < ROWS; ++r) {
            s0[r] = float4{0.f, 0.f, 0.f, 0.f};
            s1[r] = float4{0.f, 0.f, 0.f, 0.f};
        }

        const float* wp = wp0;             // uniform, SALU-advanced
        const float* hj = &hl[pp * 512];   // LDS base, one v_add per iter
        // 42 iters x 3 groups (g0..g125); lookahead 2 groups (~1024 FMA-cyc).
        #pragma unroll 1
        for (int i = 0; i < 42; ++i) {
            LOADG(C, wp, 8);   FMAG(A, 0);     // load g3i+2, fma g3i
            LOADG(A, wp, 12);  FMAG(B, 4);     // load g3i+3, fma g3i+1
            LOADG(B, wp, 16);  FMAG(C, 8);     // load g3i+4, fma g3i+2
            wp += 12 * HID;
            hj += 12;
        }
        // tail: A=g126, B=g127 (loaded at i=41); prefetch next-step g0 into C
        LOADG(C, wp0, 0);
        FMAG(A, 0);                            // g126 (j=504..507)
        FMAG(B, 4);                            // g127 (j=508..511)

        // publish the half the OTHER panel-group finishes (static indices)
        if (pp == 0) {
            PUBROW(4); PUBROW(5); PUBROW(6); PUBROW(7);
        } else {
            PUBROW(0); PUBROW(1); PUBROW(2); PUBROW(3);
        }
        __syncthreads();   // h_t reads done; sb halves visible

        // finish own half (static indices; g = s_own + s_other, commutative)
        if (pp == 0) {
            FINISH_ROW(0); FINISH_ROW(1); FINISH_ROW(2); FINISH_ROW(3);
        } else {
            FINISH_ROW(4); FINISH_ROW(5); FINISH_ROW(6); FINISH_ROW(7);
        }
        __syncthreads();   // h_{t+1} visible to all
    }

    // Epilogue: out = h_T @ W_ph + b_p (order-insensitive at bf16 threshold)
    if (tid < ROWS * NCLS) {
        const int r = tid / NCLS, k = tid - r * NCLS;
        float acc = bp[k];
        for (int j = 0; j < HID; ++j)
            acc = __fmaf_rn(hl[r * HID + j], W_ph[j * NCLS + k], acc);
        out[(size_t)(row0 + r) * NCLS + k] = acc;
    }
}

extern "C" void kernel_launch(void* const* d_in, const int* in_sizes, int n_in,
                              void* d_out, int out_size, void* d_ws, size_t ws_size,
                              hipStream_t stream) {
    const float* x    = (const float*)d_in[0];
    const float* W_hx = (const float*)d_in[1];
    const float* Whh  = (const float*)d_in[2];
    const float* W_ph = (const float*)d_in[3];
    const float* bh   = (const float*)d_in[4];
    const float* bp   = (const float*)d_in[5];
    float* out = (float*)d_out;

    rnn_win<<<2048 / ROWS, TPB, 0, stream>>>(x, W_hx, Whh, W_ph, bh, bp, out);
}